// Round 16
// baseline (1065.821 us; speedup 1.0000x reference)
//
#include <hip/hip_runtime.h>
#include <hip/hip_bf16.h>
#include <hip/hip_fp16.h>

#define N_MOL 128
#define STRESS_FLOATS (N_MOL * 9)   // 1152
#define NB 128                      // buckets
#define APB 1563                    // atoms/bucket: 128*1563 = 200064 >= 200000
#define NPAD (NB * APB)             // padded atom count
#define EPB 1024                    // edges per scatter block
#define K_PT 4                      // EPB / BLK
#define BLK 256
#define RS_SLICES 16
#define STRESS_BLOCKS 2048

// ---------------------------------------------------------------------------
__global__ void zero_i32_kernel(int* __restrict__ p, int n) {
    int i = blockIdx.x * blockDim.x + threadIdx.x;
    if (i < n) p[i] = 0;
}

__device__ __forceinline__ unsigned short h16(float v) {
    return __half_as_ushort(__float2half_rn(v));
}

// ---------------------------------------------------------------------------
// Stress kernel (separate from binning): grid-stride over ALL edges, LDS
// molecule accumulation (measured cheap), spart[blockIdx] = smem (no zeroing).
// ---------------------------------------------------------------------------
__global__ void __launch_bounds__(256)
stress_kernel(const float* __restrict__ dEdRij,
              const float* __restrict__ Rij,
              const int*   __restrict__ idx_i,
              const int*   __restrict__ idx_m,
              float* __restrict__ spart,   // [STRESS_BLOCKS][1152]
              int E)
{
    __shared__ float smem[STRESS_FLOATS];
    for (int t = threadIdx.x; t < STRESS_FLOATS; t += blockDim.x) smem[t] = 0.f;
    __syncthreads();

    const int stride = gridDim.x * blockDim.x;
    for (int e = blockIdx.x * blockDim.x + threadIdx.x; e < E; e += stride) {
        const int i = idx_i[e];
        const int m = idx_m[i];
        const float dx = dEdRij[3*e+0], dy = dEdRij[3*e+1], dz = dEdRij[3*e+2];
        const float rx = Rij[3*e+0],    ry = Rij[3*e+1],    rz = Rij[3*e+2];
        float* s = &smem[m * 9];
        atomicAdd(&s[0], rx * dx);
        atomicAdd(&s[1], rx * dy);
        atomicAdd(&s[2], rx * dz);
        atomicAdd(&s[3], ry * dx);
        atomicAdd(&s[4], ry * dy);
        atomicAdd(&s[5], ry * dz);
        atomicAdd(&s[6], rz * dx);
        atomicAdd(&s[7], rz * dy);
        atomicAdd(&s[8], rz * dz);
    }

    __syncthreads();
    float* sp = spart + (size_t)blockIdx.x * STRESS_FLOATS;
    for (int t = threadIdx.x; t < STRESS_FLOATS; t += blockDim.x)
        sp[t] = smem[t];
}

// ---------------------------------------------------------------------------
// Pass C (slimmed): pure binning. histogram -> wave0 shfl scan ->
// reservation -> bucket-major 8B-record LDS staging -> coalesced stream-out.
// LDS ~20.5 KB -> 7 blocks/CU.
// ---------------------------------------------------------------------------
__global__ void __launch_bounds__(256)
scatter_kernel(const float* __restrict__ dEdRij,
               const int*   __restrict__ idx_i,
               const int*   __restrict__ idx_j,
               uint2* __restrict__ rec,     // [NB][CAP]
               int*   __restrict__ cnt,     // [NB] (this chunk's slice)
               int e0_chunk, int n_edges_chunk, int CAP)
{
    __shared__ int           hist[NB];
    __shared__ int           excl[NB];
    __shared__ int           cur[NB];
    __shared__ int           shiftb[NB];
    __shared__ uint2         stg[EPB * 2];      // 16 KB
    __shared__ unsigned char stgb[EPB * 2];     // bucket ids, 2 KB

    for (int t = threadIdx.x; t < NB; t += blockDim.x) hist[t] = 0;
    __syncthreads();

    const int be0 = e0_chunk + blockIdx.x * EPB;
    const int be1 = min(be0 + EPB, e0_chunk + n_edges_chunk);

    // ---- phase 1: idx loads into regs + LDS histogram
    int ei[K_PT], ej[K_PT];
    #pragma unroll
    for (int k = 0; k < K_PT; ++k) {
        const int e = be0 + k * BLK + threadIdx.x;
        ei[k] = -1; ej[k] = -1;
        if (e < be1) {
            ei[k] = idx_i[e];
            ej[k] = idx_j[e];
            atomicAdd(&hist[ei[k] / APB], 1);
            atomicAdd(&hist[ej[k] / APB], 1);
        }
    }
    __syncthreads();                       // histogram complete (r11 lesson)

    // ---- wave-0 exclusive scan over NB=128 (2 entries/lane, shfl)
    if (threadIdx.x < 64) {
        const int l = threadIdx.x;
        const int a = hist[2 * l], b = hist[2 * l + 1];
        int s = a + b;
        #pragma unroll
        for (int off = 1; off < 64; off <<= 1) {
            const int v = __shfl_up(s, off, 64);
            if (l >= off) s += v;
        }
        const int excl_pair = s - (a + b);
        excl[2 * l]     = excl_pair;
        excl[2 * l + 1] = excl_pair + a;
    }
    __syncthreads();

    // ---- reservation: one global atomic per non-empty bucket
    for (int t = threadIdx.x; t < NB; t += blockDim.x) {
        const int h  = hist[t];
        const int ex = excl[t];
        const int g  = h ? atomicAdd(&cnt[t], h) : 0;
        cur[t]    = ex;
        shiftb[t] = t * CAP + g - ex;     // rec idx = stg idx + shift
    }
    __syncthreads();

    // ---- phase 2: float loads, pack, bucket-major staging
    #pragma unroll
    for (int k = 0; k < K_PT; ++k) {
        const int e = be0 + k * BLK + threadIdx.x;
        if (e >= be1) continue;
        const int i = ei[k], j = ej[k];
        const float dx = dEdRij[3*e+0], dy = dEdRij[3*e+1], dz = dEdRij[3*e+2];

        const int bi = i / APB;
        const int li = i - bi * APB;
        uint2 q;
        q.x = ((unsigned)li << 16) | h16(dx);
        q.y = (unsigned)h16(dy) | ((unsigned)h16(dz) << 16);
        int p = atomicAdd(&cur[bi], 1);
        stg[p] = q; stgb[p] = (unsigned char)bi;

        const int bj = j / APB;
        const int lj = j - bj * APB;
        q.x = ((unsigned)lj << 16) | h16(-dx);
        q.y = (unsigned)h16(-dy) | ((unsigned)h16(-dz) << 16);
        p = atomicAdd(&cur[bj], 1);
        stg[p] = q; stgb[p] = (unsigned char)bj;
    }
    __syncthreads();

    // ---- stream-out: bucket-major runs -> coalesced
    const int total = 2 * (be1 - be0);
    for (int t = threadIdx.x; t < total; t += blockDim.x) {
        const int b = stgb[t];
        const int gidx = t + shiftb[b];
        if (gidx < (b + 1) * CAP)          // capacity guard (drop-only)
            rec[gidx] = stg[t];
    }
}

// ---------------------------------------------------------------------------
// Pass D: S blocks per bucket. uint4 paired loads, 8-deep unroll (16x the
// bytes in flight vs r15). STORE=1 on chunk 0 (no pre-zero, no RMW read).
// ---------------------------------------------------------------------------
__global__ void __launch_bounds__(256)
accum_kernel(const uint2* __restrict__ rec,
             const int*   __restrict__ cnt,
             float* __restrict__ partial,   // [S][NPAD*3]
             int CAP, int S, int store)
{
    __shared__ float facc[APB * 3];        // 18.8 KB
    const int b = blockIdx.x / S;
    const int s = blockIdx.x - b * S;
    for (int t = threadIdx.x; t < APB * 3; t += blockDim.x) facc[t] = 0.f;
    __syncthreads();

    int n = cnt[b];
    if (n > CAP) n = CAP;
    int r0 = (int)((long long)n * s / S);
    int r1 = (int)((long long)n * (s + 1) / S);
    const uint2* rb = rec + (size_t)b * CAP;

#define ACC1(w0, w1)                                                  \
    {                                                                 \
        const int   l  = (int)((w0) >> 16);                           \
        const float fx = __half2float(__ushort_as_half(               \
                             (unsigned short)((w0) & 0xffffu)));      \
        const float fy = __half2float(__ushort_as_half(               \
                             (unsigned short)((w1) & 0xffffu)));      \
        const float fz = __half2float(__ushort_as_half(               \
                             (unsigned short)((w1) >> 16)));          \
        atomicAdd(&facc[l * 3 + 0], fx);                              \
        atomicAdd(&facc[l * 3 + 1], fy);                              \
        atomicAdd(&facc[l * 3 + 2], fz);                              \
    }

    // scalar head/tail to even-pair alignment (CAP is even, rb 16B-aligned)
    if (r0 < r1 && (r0 & 1)) {
        if (threadIdx.x == 0) { const uint2 q = rb[r0]; ACC1(q.x, q.y); }
        ++r0;
    }
    if (r0 < r1 && (r1 & 1)) {
        --r1;
        if (threadIdx.x == 0) { const uint2 q = rb[r1]; ACC1(q.x, q.y); }
    }
    const int npair = (r1 - r0) >> 1;
    const uint4* rp = (const uint4*)(rb + r0);

    int p = threadIdx.x;
    for (; p + 7 * BLK < npair; p += 8 * BLK) {
        uint4 q0 = rp[p];
        uint4 q1 = rp[p + 1 * BLK];
        uint4 q2 = rp[p + 2 * BLK];
        uint4 q3 = rp[p + 3 * BLK];
        uint4 q4 = rp[p + 4 * BLK];
        uint4 q5 = rp[p + 5 * BLK];
        uint4 q6 = rp[p + 6 * BLK];
        uint4 q7 = rp[p + 7 * BLK];
        ACC1(q0.x, q0.y); ACC1(q0.z, q0.w);
        ACC1(q1.x, q1.y); ACC1(q1.z, q1.w);
        ACC1(q2.x, q2.y); ACC1(q2.z, q2.w);
        ACC1(q3.x, q3.y); ACC1(q3.z, q3.w);
        ACC1(q4.x, q4.y); ACC1(q4.z, q4.w);
        ACC1(q5.x, q5.y); ACC1(q5.z, q5.w);
        ACC1(q6.x, q6.y); ACC1(q6.z, q6.w);
        ACC1(q7.x, q7.y); ACC1(q7.z, q7.w);
    }
    for (; p < npair; p += BLK) {
        const uint4 q = rp[p];
        ACC1(q.x, q.y); ACC1(q.z, q.w);
    }
#undef ACC1

    __syncthreads();
    float* pp = partial + ((size_t)s * NPAD + (size_t)b * APB) * 3;
    if (store) {
        for (int t = threadIdx.x; t < APB * 3; t += blockDim.x)
            pp[t] = facc[t];
    } else {
        for (int t = threadIdx.x; t < APB * 3; t += blockDim.x)
            pp[t] += facc[t];
    }
}

// ---------------------------------------------------------------------------
// forces = sum_s partial[s]  (full overwrite of d_out forces region)
// ---------------------------------------------------------------------------
__global__ void final_forces_kernel(const float* __restrict__ partial,
                                    float* __restrict__ forces, int n3, int S)
{
    const int t = blockIdx.x * blockDim.x + threadIdx.x;
    if (t >= n3) return;
    float a = 0.f;
    for (int s = 0; s < S; ++s)
        a += partial[(size_t)s * NPAD * 3 + t];
    forces[t] = a;
}

// ---------------------------------------------------------------------------
// Stress reduce, 2-stage (rows = STRESS_BLOCKS; stage1 coalesced per-row)
// ---------------------------------------------------------------------------
__global__ void reduce_stress_stage1(const float* __restrict__ spart,
                                     float* __restrict__ stmp, int rows)
{
    const int t = blockIdx.x * blockDim.x + threadIdx.x;
    if (t >= STRESS_FLOATS * RS_SLICES) return;
    const int col = t % STRESS_FLOATS;
    const int sl  = t / STRESS_FLOATS;
    float acc = 0.f;
    for (int r = sl; r < rows; r += RS_SLICES)
        acc += spart[(size_t)r * STRESS_FLOATS + col];
    stmp[sl * STRESS_FLOATS + col] = acc;
}

__global__ void reduce_stress_stage2(const float* __restrict__ stmp,
                                     const float* __restrict__ cell,
                                     float* __restrict__ out_stress)
{
    const int t = blockIdx.x * blockDim.x + threadIdx.x;
    if (t >= STRESS_FLOATS) return;
    float acc = 0.f;
    #pragma unroll
    for (int s = 0; s < RS_SLICES; ++s)
        acc += stmp[s * STRESS_FLOATS + t];
    const int m = t / 9;
    const float* c = &cell[m * 9];
    const float a0 = c[0], a1 = c[1], a2 = c[2];
    const float b0 = c[3], b1 = c[4], b2 = c[5];
    const float c0 = c[6], c1 = c[7], c2 = c[8];
    const float x0 = b1 * c2 - b2 * c1;
    const float x1 = b2 * c0 - b0 * c2;
    const float x2 = b0 * c1 - b1 * c0;
    const float vol = a0 * x0 + a1 * x1 + a2 * x2;
    out_stress[t] = acc / vol;
}

// ===========================================================================
// Fallback: round-6 measured f64 atomic path (known passing)
// ===========================================================================
__global__ void zero_f64_kernel(double* __restrict__ p, int n) {
    int i = blockIdx.x * blockDim.x + threadIdx.x;
    if (i < n) p[i] = 0.0;
}

__global__ void __launch_bounds__(256)
edge_kernel_f64(const float* __restrict__ dEdRij,
                const float* __restrict__ Rij,
                const int*   __restrict__ idx_i,
                const int*   __restrict__ idx_j,
                const int*   __restrict__ idx_m,
                double* __restrict__ facc,
                float*  __restrict__ spart,
                int E)
{
    __shared__ float smem[STRESS_FLOATS];
    for (int t = threadIdx.x; t < STRESS_FLOATS; t += blockDim.x) smem[t] = 0.f;
    __syncthreads();
    const int stride = gridDim.x * blockDim.x;
    for (int e = blockIdx.x * blockDim.x + threadIdx.x; e < E; e += stride) {
        const int i = idx_i[e], j = idx_j[e];
        const float dx = dEdRij[3*e+0], dy = dEdRij[3*e+1], dz = dEdRij[3*e+2];
        const float rx = Rij[3*e+0],    ry = Rij[3*e+1],    rz = Rij[3*e+2];
        double* fi = facc + 3 * (size_t)i;
        unsafeAtomicAdd(fi + 0, (double) dx);
        unsafeAtomicAdd(fi + 1, (double) dy);
        unsafeAtomicAdd(fi + 2, (double) dz);
        double* fj = facc + 3 * (size_t)j;
        unsafeAtomicAdd(fj + 0, (double)-dx);
        unsafeAtomicAdd(fj + 1, (double)-dy);
        unsafeAtomicAdd(fj + 2, (double)-dz);
        const int m = idx_m[i];
        float* s = &smem[m * 9];
        atomicAdd(&s[0], rx*dx); atomicAdd(&s[1], rx*dy); atomicAdd(&s[2], rx*dz);
        atomicAdd(&s[3], ry*dx); atomicAdd(&s[4], ry*dy); atomicAdd(&s[5], ry*dz);
        atomicAdd(&s[6], rz*dx); atomicAdd(&s[7], rz*dy); atomicAdd(&s[8], rz*dz);
    }
    __syncthreads();
    float* sp = spart + (size_t)blockIdx.x * STRESS_FLOATS;
    for (int t = threadIdx.x; t < STRESS_FLOATS; t += blockDim.x) sp[t] = smem[t];
}

__global__ void reduce_forces_f64_kernel(const double* __restrict__ facc,
                                         float* __restrict__ forces, int n3)
{
    int t = blockIdx.x * blockDim.x + threadIdx.x;
    if (t < n3) forces[t] = (float)facc[t];
}

// ===========================================================================
extern "C" void kernel_launch(void* const* d_in, const int* in_sizes, int n_in,
                              void* d_out, int out_size, void* d_ws, size_t ws_size,
                              hipStream_t stream)
{
    const float* dEdRij = (const float*)d_in[0];
    const float* Rij    = (const float*)d_in[1];
    const float* R      = (const float*)d_in[2];  (void)R;
    const float* cell   = (const float*)d_in[3];
    const int*   idx_i  = (const int*)d_in[4];
    const int*   idx_j  = (const int*)d_in[5];
    const int*   idx_m  = (const int*)d_in[6];

    const int E  = in_sizes[0] / 3;   // 10,000,000
    const int N  = in_sizes[2] / 3;   // 200,000
    const int n3 = N * 3;

    float* out        = (float*)d_out;
    float* forces     = out;
    float* stress_out = out + (size_t)n3;

    // ---- (nc, S) priority search. need =
    //  rec[NB][CAP]*8B + spart[2048][1152]*4B + cnt[nc][NB]*4B
    //  + stmp[16][1152]*4B + partial[S][NPAD*3]*4B
    int nchunks = 0, SEG = 0, CAP = 0;
    size_t rec_u2 = 0;
    const size_t spart_f = (size_t)STRESS_BLOCKS * STRESS_FLOATS;
    {
        const int cand[14][2] = {
            {2,16},{2,8},{3,16},{3,8},{2,4},{4,8},{4,4},{2,2},
            {5,4},{8,4},{10,2},{16,2},{20,2},{40,1}};
        for (int ci = 0; ci < 14; ++ci) {
            const int nc = cand[ci][0];
            const int S  = cand[ci][1];
            const int CH = (E + nc - 1) / nc;
            const long long mean = 2LL * CH / NB;
            int cap = (int)(mean + mean / 8 + 64);   // ~35 sigma headroom
            cap = (cap + 1) & ~1;                    // even: 16B pair alignment
            const size_t need = (size_t)NB * cap * sizeof(uint2)
                              + spart_f * sizeof(float)
                              + (size_t)nc * NB * sizeof(int)
                              + (size_t)RS_SLICES * STRESS_FLOATS * sizeof(float)
                              + (size_t)S * NPAD * 3 * sizeof(float)
                              + 256;
            if (need <= ws_size) {
                nchunks = nc; SEG = S; CAP = cap;
                rec_u2  = (size_t)NB * cap;
                break;
            }
        }
    }

    if (nchunks > 0) {
        uint2* rec   = (uint2*)d_ws;
        float* spart = (float*)(rec + rec_u2);
        int*   cnt   = (int*)(spart + spart_f);               // [nc][NB]
        float* stmp  = (float*)(cnt + (size_t)nchunks * NB);  // [16][1152]
        float* part  = stmp + (size_t)RS_SLICES * STRESS_FLOATS; // [S][NPAD*3]

        // only cnt needs zeroing (spart/stmp/partial are fully overwritten)
        zero_i32_kernel<<<(nchunks * NB + BLK - 1) / BLK, BLK, 0, stream>>>(
            cnt, nchunks * NB);

        stress_kernel<<<STRESS_BLOCKS, BLK, 0, stream>>>(
            dEdRij, Rij, idx_i, idx_m, spart, E);

        const int CH = (E + nchunks - 1) / nchunks;
        int chunk = 0;
        for (int s = 0; s < E; s += CH, ++chunk) {
            const int ce = min(CH, E - s);
            const int nb = (ce + EPB - 1) / EPB;

            scatter_kernel<<<nb, BLK, 0, stream>>>(
                dEdRij, idx_i, idx_j,
                rec, cnt + (size_t)chunk * NB, s, ce, CAP);

            accum_kernel<<<NB * SEG, BLK, 0, stream>>>(
                rec, cnt + (size_t)chunk * NB, part, CAP, SEG,
                chunk == 0 ? 1 : 0);
        }

        final_forces_kernel<<<(n3 + BLK - 1) / BLK, BLK, 0, stream>>>(
            part, forces, n3, SEG);
        reduce_stress_stage1<<<(STRESS_FLOATS * RS_SLICES + BLK - 1) / BLK,
                               BLK, 0, stream>>>(spart, stmp, STRESS_BLOCKS);
        reduce_stress_stage2<<<(STRESS_FLOATS + BLK - 1) / BLK, BLK, 0, stream>>>(
            stmp, cell, stress_out);
    } else {
        // fallback: measured f64 atomic path
        double* facc   = (double*)d_ws;
        float*  spartf = (float*)(facc + n3);

        zero_f64_kernel<<<(n3 + BLK - 1) / BLK, BLK, 0, stream>>>(facc, n3);
        edge_kernel_f64<<<2048, BLK, 0, stream>>>(
            dEdRij, Rij, idx_i, idx_j, idx_m, facc, spartf, E);
        reduce_forces_f64_kernel<<<(n3 + BLK - 1) / BLK, BLK, 0, stream>>>(
            facc, forces, n3);
        reduce_stress_stage1<<<(STRESS_FLOATS * RS_SLICES + BLK - 1) / BLK,
                               BLK, 0, stream>>>(spartf, (float*)(spartf + (size_t)2048 * STRESS_FLOATS), 2048);
        reduce_stress_stage2<<<(STRESS_FLOATS + BLK - 1) / BLK, BLK, 0, stream>>>(
            (float*)(spartf + (size_t)2048 * STRESS_FLOATS), cell, stress_out);
    }
}

// Round 18
// 1064.378 us; speedup vs baseline: 1.0014x; 1.0014x over previous
//
#include <hip/hip_runtime.h>
#include <hip/hip_bf16.h>
#include <hip/hip_fp16.h>

#define N_MOL 128
#define STRESS_FLOATS (N_MOL * 9)   // 1152
#define NB 128                      // buckets
#define APB 1563                    // atoms/bucket: 128*1563 = 200064 >= 200000
#define NPAD (NB * APB)             // padded atom count
#define EPB 1024                    // edges per scatter block
#define K_PT 4                      // EPB / BLK
#define BLK 256
#define RS_SLICES 16
#define STRESS_BLOCKS 2048
#define SB 4                        // stress batch depth (latency hiding)

// ---------------------------------------------------------------------------
__global__ void zero_i32_kernel(int* __restrict__ p, int n) {
    int i = blockIdx.x * blockDim.x + threadIdx.x;
    if (i < n) p[i] = 0;
}

__device__ __forceinline__ unsigned short h16(float v) {
    return __half_as_ushort(__float2half_rn(v));
}

// ---------------------------------------------------------------------------
// Stress kernel, 4-edge batched to break the idx_i -> idx_m -> atomic
// dependent chain (r16: 460us latency-bound at 1 edge/thread/round).
// All loads within a batch are independent; stall paid once per 4 edges.
// ---------------------------------------------------------------------------
__global__ void __launch_bounds__(256)
stress_kernel(const float* __restrict__ dEdRij,
              const float* __restrict__ Rij,
              const int*   __restrict__ idx_i,
              const int*   __restrict__ idx_m,
              float* __restrict__ spart,   // [STRESS_BLOCKS][1152]
              int E)
{
    __shared__ float smem[STRESS_FLOATS];
    for (int t = threadIdx.x; t < STRESS_FLOATS; t += blockDim.x) smem[t] = 0.f;
    __syncthreads();

    const int stride = gridDim.x * blockDim.x;
    const int base   = blockIdx.x * blockDim.x + threadIdx.x;

    for (int e0 = base; e0 < E; e0 += stride * SB) {
        int   ia[SB], ma[SB], ec[SB];
        bool  v[SB];
        float d0[SB], d1[SB], d2[SB], r0[SB], r1[SB], r2[SB];

        // 4 independent idx_i loads
        #pragma unroll
        for (int u = 0; u < SB; ++u) {
            const int e = e0 + u * stride;
            v[u]  = (e < E);
            ec[u] = v[u] ? e : e0;          // clamp: harmless re-read
            ia[u] = idx_i[ec[u]];
        }
        // 4 independent idx_m gathers (L2)
        #pragma unroll
        for (int u = 0; u < SB; ++u) ma[u] = idx_m[ia[u]];
        // 24 independent float loads
        #pragma unroll
        for (int u = 0; u < SB; ++u) {
            const int e = ec[u];
            d0[u] = dEdRij[3*e+0]; d1[u] = dEdRij[3*e+1]; d2[u] = dEdRij[3*e+2];
            r0[u] = Rij[3*e+0];    r1[u] = Rij[3*e+1];    r2[u] = Rij[3*e+2];
        }
        // LDS accumulation
        #pragma unroll
        for (int u = 0; u < SB; ++u) {
            if (!v[u]) continue;
            float* s = &smem[ma[u] * 9];
            atomicAdd(&s[0], r0[u] * d0[u]);
            atomicAdd(&s[1], r0[u] * d1[u]);
            atomicAdd(&s[2], r0[u] * d2[u]);
            atomicAdd(&s[3], r1[u] * d0[u]);
            atomicAdd(&s[4], r1[u] * d1[u]);
            atomicAdd(&s[5], r1[u] * d2[u]);
            atomicAdd(&s[6], r2[u] * d0[u]);
            atomicAdd(&s[7], r2[u] * d1[u]);
            atomicAdd(&s[8], r2[u] * d2[u]);
        }
    }

    __syncthreads();
    float* sp = spart + (size_t)blockIdx.x * STRESS_FLOATS;
    for (int t = threadIdx.x; t < STRESS_FLOATS; t += blockDim.x)
        sp[t] = smem[t];
}

// ---------------------------------------------------------------------------
// Pass C (slim binning, measured ~210us/5M-edge chunk): histogram -> wave0
// shfl scan -> reservation -> bucket-major 8B-record staging -> stream-out.
// ---------------------------------------------------------------------------
__global__ void __launch_bounds__(256)
scatter_kernel(const float* __restrict__ dEdRij,
               const int*   __restrict__ idx_i,
               const int*   __restrict__ idx_j,
               uint2* __restrict__ rec,     // [NB][CAP]
               int*   __restrict__ cnt,     // [NB] (this chunk's slice)
               int e0_chunk, int n_edges_chunk, int CAP)
{
    __shared__ int           hist[NB];
    __shared__ int           excl[NB];
    __shared__ int           cur[NB];
    __shared__ int           shiftb[NB];
    __shared__ uint2         stg[EPB * 2];      // 16 KB
    __shared__ unsigned char stgb[EPB * 2];     // bucket ids, 2 KB

    for (int t = threadIdx.x; t < NB; t += blockDim.x) hist[t] = 0;
    __syncthreads();

    const int be0 = e0_chunk + blockIdx.x * EPB;
    const int be1 = min(be0 + EPB, e0_chunk + n_edges_chunk);

    // ---- phase 1: idx loads into regs + LDS histogram
    int ei[K_PT], ej[K_PT];
    #pragma unroll
    for (int k = 0; k < K_PT; ++k) {
        const int e = be0 + k * BLK + threadIdx.x;
        ei[k] = -1; ej[k] = -1;
        if (e < be1) {
            ei[k] = idx_i[e];
            ej[k] = idx_j[e];
            atomicAdd(&hist[ei[k] / APB], 1);
            atomicAdd(&hist[ej[k] / APB], 1);
        }
    }
    __syncthreads();                       // histogram complete (r11 lesson)

    // ---- wave-0 exclusive scan over NB=128 (2 entries/lane, shfl)
    if (threadIdx.x < 64) {
        const int l = threadIdx.x;
        const int a = hist[2 * l], b = hist[2 * l + 1];
        int s = a + b;
        #pragma unroll
        for (int off = 1; off < 64; off <<= 1) {
            const int v = __shfl_up(s, off, 64);
            if (l >= off) s += v;
        }
        const int excl_pair = s - (a + b);
        excl[2 * l]     = excl_pair;
        excl[2 * l + 1] = excl_pair + a;
    }
    __syncthreads();

    // ---- reservation: one global atomic per non-empty bucket
    for (int t = threadIdx.x; t < NB; t += blockDim.x) {
        const int h  = hist[t];
        const int ex = excl[t];
        const int g  = h ? atomicAdd(&cnt[t], h) : 0;
        cur[t]    = ex;
        shiftb[t] = t * CAP + g - ex;     // rec idx = stg idx + shift
    }
    __syncthreads();

    // ---- phase 2: float loads, pack, bucket-major staging
    #pragma unroll
    for (int k = 0; k < K_PT; ++k) {
        const int e = be0 + k * BLK + threadIdx.x;
        if (e >= be1) continue;
        const int i = ei[k], j = ej[k];
        const float dx = dEdRij[3*e+0], dy = dEdRij[3*e+1], dz = dEdRij[3*e+2];

        const int bi = i / APB;
        const int li = i - bi * APB;
        uint2 q;
        q.x = ((unsigned)li << 16) | h16(dx);
        q.y = (unsigned)h16(dy) | ((unsigned)h16(dz) << 16);
        int p = atomicAdd(&cur[bi], 1);
        stg[p] = q; stgb[p] = (unsigned char)bi;

        const int bj = j / APB;
        const int lj = j - bj * APB;
        q.x = ((unsigned)lj << 16) | h16(-dx);
        q.y = (unsigned)h16(-dy) | ((unsigned)h16(-dz) << 16);
        p = atomicAdd(&cur[bj], 1);
        stg[p] = q; stgb[p] = (unsigned char)bj;
    }
    __syncthreads();

    // ---- stream-out: bucket-major runs -> coalesced
    const int total = 2 * (be1 - be0);
    for (int t = threadIdx.x; t < total; t += blockDim.x) {
        const int b = stgb[t];
        const int gidx = t + shiftb[b];
        if (gidx < (b + 1) * CAP)          // capacity guard (drop-only)
            rec[gidx] = stg[t];
    }
}

// ---------------------------------------------------------------------------
// Pass D (measured ~60-70us/chunk): S blocks per bucket, uint4 paired loads,
// 8-deep unroll. STORE=1 on chunk 0 (no pre-zero, no RMW read).
// ---------------------------------------------------------------------------
__global__ void __launch_bounds__(256)
accum_kernel(const uint2* __restrict__ rec,
             const int*   __restrict__ cnt,
             float* __restrict__ partial,   // [S][NPAD*3]
             int CAP, int S, int store)
{
    __shared__ float facc[APB * 3];        // 18.8 KB
    const int b = blockIdx.x / S;
    const int s = blockIdx.x - b * S;
    for (int t = threadIdx.x; t < APB * 3; t += blockDim.x) facc[t] = 0.f;
    __syncthreads();

    int n = cnt[b];
    if (n > CAP) n = CAP;
    int r0 = (int)((long long)n * s / S);
    int r1 = (int)((long long)n * (s + 1) / S);
    const uint2* rb = rec + (size_t)b * CAP;

#define ACC1(w0, w1)                                                  \
    {                                                                 \
        const int   l  = (int)((w0) >> 16);                           \
        const float fx = __half2float(__ushort_as_half(               \
                             (unsigned short)((w0) & 0xffffu)));      \
        const float fy = __half2float(__ushort_as_half(               \
                             (unsigned short)((w1) & 0xffffu)));      \
        const float fz = __half2float(__ushort_as_half(               \
                             (unsigned short)((w1) >> 16)));          \
        atomicAdd(&facc[l * 3 + 0], fx);                              \
        atomicAdd(&facc[l * 3 + 1], fy);                              \
        atomicAdd(&facc[l * 3 + 2], fz);                              \
    }

    if (r0 < r1 && (r0 & 1)) {
        if (threadIdx.x == 0) { const uint2 q = rb[r0]; ACC1(q.x, q.y); }
        ++r0;
    }
    if (r0 < r1 && (r1 & 1)) {
        --r1;
        if (threadIdx.x == 0) { const uint2 q = rb[r1]; ACC1(q.x, q.y); }
    }
    const int npair = (r1 - r0) >> 1;
    const uint4* rp = (const uint4*)(rb + r0);

    int p = threadIdx.x;
    for (; p + 7 * BLK < npair; p += 8 * BLK) {
        uint4 q0 = rp[p];
        uint4 q1 = rp[p + 1 * BLK];
        uint4 q2 = rp[p + 2 * BLK];
        uint4 q3 = rp[p + 3 * BLK];
        uint4 q4 = rp[p + 4 * BLK];
        uint4 q5 = rp[p + 5 * BLK];
        uint4 q6 = rp[p + 6 * BLK];
        uint4 q7 = rp[p + 7 * BLK];
        ACC1(q0.x, q0.y); ACC1(q0.z, q0.w);
        ACC1(q1.x, q1.y); ACC1(q1.z, q1.w);
        ACC1(q2.x, q2.y); ACC1(q2.z, q2.w);
        ACC1(q3.x, q3.y); ACC1(q3.z, q3.w);
        ACC1(q4.x, q4.y); ACC1(q4.z, q4.w);
        ACC1(q5.x, q5.y); ACC1(q5.z, q5.w);
        ACC1(q6.x, q6.y); ACC1(q6.z, q6.w);
        ACC1(q7.x, q7.y); ACC1(q7.z, q7.w);
    }
    for (; p < npair; p += BLK) {
        const uint4 q = rp[p];
        ACC1(q.x, q.y); ACC1(q.z, q.w);
    }
#undef ACC1

    __syncthreads();
    float* pp = partial + ((size_t)s * NPAD + (size_t)b * APB) * 3;
    if (store) {
        for (int t = threadIdx.x; t < APB * 3; t += blockDim.x)
            pp[t] = facc[t];
    } else {
        for (int t = threadIdx.x; t < APB * 3; t += blockDim.x)
            pp[t] += facc[t];
    }
}

// ---------------------------------------------------------------------------
__global__ void final_forces_kernel(const float* __restrict__ partial,
                                    float* __restrict__ forces, int n3, int S)
{
    const int t = blockIdx.x * blockDim.x + threadIdx.x;
    if (t >= n3) return;
    float a = 0.f;
    for (int s = 0; s < S; ++s)
        a += partial[(size_t)s * NPAD * 3 + t];
    forces[t] = a;
}

// ---------------------------------------------------------------------------
__global__ void reduce_stress_stage1(const float* __restrict__ spart,
                                     float* __restrict__ stmp, int rows)
{
    const int t = blockIdx.x * blockDim.x + threadIdx.x;
    if (t >= STRESS_FLOATS * RS_SLICES) return;
    const int col = t % STRESS_FLOATS;
    const int sl  = t / STRESS_FLOATS;
    float acc = 0.f;
    for (int r = sl; r < rows; r += RS_SLICES)
        acc += spart[(size_t)r * STRESS_FLOATS + col];
    stmp[sl * STRESS_FLOATS + col] = acc;
}

__global__ void reduce_stress_stage2(const float* __restrict__ stmp,
                                     const float* __restrict__ cell,
                                     float* __restrict__ out_stress)
{
    const int t = blockIdx.x * blockDim.x + threadIdx.x;
    if (t >= STRESS_FLOATS) return;
    float acc = 0.f;
    #pragma unroll
    for (int s = 0; s < RS_SLICES; ++s)
        acc += stmp[s * STRESS_FLOATS + t];
    const int m = t / 9;
    const float* c = &cell[m * 9];
    const float a0 = c[0], a1 = c[1], a2 = c[2];
    const float b0 = c[3], b1 = c[4], b2 = c[5];
    const float c0 = c[6], c1 = c[7], c2 = c[8];
    const float x0 = b1 * c2 - b2 * c1;
    const float x1 = b2 * c0 - b0 * c2;
    const float x2 = b0 * c1 - b1 * c0;
    const float vol = a0 * x0 + a1 * x1 + a2 * x2;
    out_stress[t] = acc / vol;
}

// ===========================================================================
// Fallback: round-6 measured f64 atomic path (known passing)
// ===========================================================================
__global__ void zero_f64_kernel(double* __restrict__ p, int n) {
    int i = blockIdx.x * blockDim.x + threadIdx.x;
    if (i < n) p[i] = 0.0;
}

__global__ void __launch_bounds__(256)
edge_kernel_f64(const float* __restrict__ dEdRij,
                const float* __restrict__ Rij,
                const int*   __restrict__ idx_i,
                const int*   __restrict__ idx_j,
                const int*   __restrict__ idx_m,
                double* __restrict__ facc,
                float*  __restrict__ spart,
                int E)
{
    __shared__ float smem[STRESS_FLOATS];
    for (int t = threadIdx.x; t < STRESS_FLOATS; t += blockDim.x) smem[t] = 0.f;
    __syncthreads();
    const int stride = gridDim.x * blockDim.x;
    for (int e = blockIdx.x * blockDim.x + threadIdx.x; e < E; e += stride) {
        const int i = idx_i[e], j = idx_j[e];
        const float dx = dEdRij[3*e+0], dy = dEdRij[3*e+1], dz = dEdRij[3*e+2];
        const float rx = Rij[3*e+0],    ry = Rij[3*e+1],    rz = Rij[3*e+2];
        double* fi = facc + 3 * (size_t)i;
        unsafeAtomicAdd(fi + 0, (double) dx);
        unsafeAtomicAdd(fi + 1, (double) dy);
        unsafeAtomicAdd(fi + 2, (double) dz);
        double* fj = facc + 3 * (size_t)j;
        unsafeAtomicAdd(fj + 0, (double)-dx);
        unsafeAtomicAdd(fj + 1, (double)-dy);
        unsafeAtomicAdd(fj + 2, (double)-dz);
        const int m = idx_m[i];
        float* s = &smem[m * 9];
        atomicAdd(&s[0], rx*dx); atomicAdd(&s[1], rx*dy); atomicAdd(&s[2], rx*dz);
        atomicAdd(&s[3], ry*dx); atomicAdd(&s[4], ry*dy); atomicAdd(&s[5], ry*dz);
        atomicAdd(&s[6], rz*dx); atomicAdd(&s[7], rz*dy); atomicAdd(&s[8], rz*dz);
    }
    __syncthreads();
    float* sp = spart + (size_t)blockIdx.x * STRESS_FLOATS;
    for (int t = threadIdx.x; t < STRESS_FLOATS; t += blockDim.x) sp[t] = smem[t];
}

__global__ void reduce_forces_f64_kernel(const double* __restrict__ facc,
                                         float* __restrict__ forces, int n3)
{
    int t = blockIdx.x * blockDim.x + threadIdx.x;
    if (t < n3) forces[t] = (float)facc[t];
}

// ===========================================================================
extern "C" void kernel_launch(void* const* d_in, const int* in_sizes, int n_in,
                              void* d_out, int out_size, void* d_ws, size_t ws_size,
                              hipStream_t stream)
{
    const float* dEdRij = (const float*)d_in[0];
    const float* Rij    = (const float*)d_in[1];
    const float* R      = (const float*)d_in[2];  (void)R;
    const float* cell   = (const float*)d_in[3];
    const int*   idx_i  = (const int*)d_in[4];
    const int*   idx_j  = (const int*)d_in[5];
    const int*   idx_m  = (const int*)d_in[6];

    const int E  = in_sizes[0] / 3;   // 10,000,000
    const int N  = in_sizes[2] / 3;   // 200,000
    const int n3 = N * 3;

    float* out        = (float*)d_out;
    float* forces     = out;
    float* stress_out = out + (size_t)n3;

    // ---- (nc, S) priority search. need =
    //  rec[NB][CAP]*8B + spart[2048][1152]*4B + cnt[nc][NB]*4B
    //  + stmp[16][1152]*4B + partial[S][NPAD*3]*4B
    int nchunks = 0, SEG = 0, CAP = 0;
    size_t rec_u2 = 0;
    const size_t spart_f = (size_t)STRESS_BLOCKS * STRESS_FLOATS;
    {
        const int cand[14][2] = {
            {2,16},{2,8},{3,16},{3,8},{2,4},{4,8},{4,4},{2,2},
            {5,4},{8,4},{10,2},{16,2},{20,2},{40,1}};
        for (int ci = 0; ci < 14; ++ci) {
            const int nc = cand[ci][0];
            const int S  = cand[ci][1];
            const int CH = (E + nc - 1) / nc;
            const long long mean = 2LL * CH / NB;
            int cap = (int)(mean + mean / 8 + 64);   // ~35 sigma headroom
            cap = (cap + 1) & ~1;                    // even: 16B pair alignment
            const size_t need = (size_t)NB * cap * sizeof(uint2)
                              + spart_f * sizeof(float)
                              + (size_t)nc * NB * sizeof(int)
                              + (size_t)RS_SLICES * STRESS_FLOATS * sizeof(float)
                              + (size_t)S * NPAD * 3 * sizeof(float)
                              + 256;
            if (need <= ws_size) {
                nchunks = nc; SEG = S; CAP = cap;
                rec_u2  = (size_t)NB * cap;
                break;
            }
        }
    }

    if (nchunks > 0) {
        uint2* rec   = (uint2*)d_ws;
        float* spart = (float*)(rec + rec_u2);
        int*   cnt   = (int*)(spart + spart_f);               // [nc][NB]
        float* stmp  = (float*)(cnt + (size_t)nchunks * NB);  // [16][1152]
        float* part  = stmp + (size_t)RS_SLICES * STRESS_FLOATS; // [S][NPAD*3]

        // only cnt needs zeroing (spart/stmp/partial fully overwritten)
        zero_i32_kernel<<<(nchunks * NB + BLK - 1) / BLK, BLK, 0, stream>>>(
            cnt, nchunks * NB);

        stress_kernel<<<STRESS_BLOCKS, BLK, 0, stream>>>(
            dEdRij, Rij, idx_i, idx_m, spart, E);

        const int CH = (E + nchunks - 1) / nchunks;
        int chunk = 0;
        for (int s = 0; s < E; s += CH, ++chunk) {
            const int ce = min(CH, E - s);
            const int nb = (ce + EPB - 1) / EPB;

            scatter_kernel<<<nb, BLK, 0, stream>>>(
                dEdRij, idx_i, idx_j,
                rec, cnt + (size_t)chunk * NB, s, ce, CAP);

            accum_kernel<<<NB * SEG, BLK, 0, stream>>>(
                rec, cnt + (size_t)chunk * NB, part, CAP, SEG,
                chunk == 0 ? 1 : 0);
        }

        final_forces_kernel<<<(n3 + BLK - 1) / BLK, BLK, 0, stream>>>(
            part, forces, n3, SEG);
        reduce_stress_stage1<<<(STRESS_FLOATS * RS_SLICES + BLK - 1) / BLK,
                               BLK, 0, stream>>>(spart, stmp, STRESS_BLOCKS);
        reduce_stress_stage2<<<(STRESS_FLOATS + BLK - 1) / BLK, BLK, 0, stream>>>(
            stmp, cell, stress_out);
    } else {
        // fallback: measured f64 atomic path
        double* facc   = (double*)d_ws;
        float*  spartf = (float*)(facc + n3);

        zero_f64_kernel<<<(n3 + BLK - 1) / BLK, BLK, 0, stream>>>(facc, n3);
        edge_kernel_f64<<<2048, BLK, 0, stream>>>(
            dEdRij, Rij, idx_i, idx_j, idx_m, facc, spartf, E);
        reduce_forces_f64_kernel<<<(n3 + BLK - 1) / BLK, BLK, 0, stream>>>(
            facc, forces, n3);
        reduce_stress_stage1<<<(STRESS_FLOATS * RS_SLICES + BLK - 1) / BLK,
                               BLK, 0, stream>>>(
            spartf, (float*)(spartf + (size_t)2048 * STRESS_FLOATS), 2048);
        reduce_stress_stage2<<<(STRESS_FLOATS + BLK - 1) / BLK, BLK, 0, stream>>>(
            (float*)(spartf + (size_t)2048 * STRESS_FLOATS), cell, stress_out);
    }
}

// Round 19
// 945.004 us; speedup vs baseline: 1.1278x; 1.1263x over previous
//
#include <hip/hip_runtime.h>
#include <hip/hip_bf16.h>
#include <hip/hip_fp16.h>

#define N_MOL 128
#define STRESS_FLOATS (N_MOL * 9)   // 1152
#define NB 128                      // buckets
#define APB 1563                    // atoms/bucket: 128*1563 = 200064 >= 200000
#define NPAD (NB * APB)             // padded atom count
#define EPB 1024                    // edges per scatter block
#define K_PT 4                      // EPB / BLK
#define BLK 256
#define RS_SLICES 64

// ---------------------------------------------------------------------------
__global__ void zero_f32_kernel(float* __restrict__ p, size_t n) {
    size_t i = (size_t)blockIdx.x * blockDim.x + threadIdx.x;
    if (i < n) p[i] = 0.f;
}

__device__ __forceinline__ unsigned short h16(float v) {
    return __half_as_ushort(__float2half_rn(v));
}

// ---------------------------------------------------------------------------
// Combined scatter+stress (r15 structure, measured 306us/5M-edge chunk;
// stress marginal cost inside is ~96us vs 460us standalone — r16/r18 lesson).
// histogram -> wave0 shfl scan -> reservation -> bucket-major 8B records ->
// coalesced stream-out; stress LDS accum -> spart[blockIdx] += (across chunks).
// ---------------------------------------------------------------------------
__global__ void __launch_bounds__(256)
scatter_kernel(const float* __restrict__ dEdRij,
               const float* __restrict__ Rij,
               const int*   __restrict__ idx_i,
               const int*   __restrict__ idx_j,
               const int*   __restrict__ idx_m,
               uint2* __restrict__ rec,     // [NB][CAP]
               int*   __restrict__ cnt,     // [NB] (this chunk's slice)
               float* __restrict__ spart,   // [ROWS][1152], += across chunks
               int e0_chunk, int n_edges_chunk, int CAP)
{
    __shared__ int           hist[NB];
    __shared__ int           excl[NB];
    __shared__ int           cur[NB];
    __shared__ int           shiftb[NB];
    __shared__ float         smem[STRESS_FLOATS];
    __shared__ uint2         stg[EPB * 2];      // 16 KB
    __shared__ unsigned char stgb[EPB * 2];     // bucket ids, 2 KB

    for (int t = threadIdx.x; t < NB; t += blockDim.x) hist[t] = 0;
    for (int t = threadIdx.x; t < STRESS_FLOATS; t += blockDim.x) smem[t] = 0.f;
    __syncthreads();

    const int be0 = e0_chunk + blockIdx.x * EPB;
    const int be1 = min(be0 + EPB, e0_chunk + n_edges_chunk);

    // ---- phase 1: idx loads into regs + LDS histogram
    int ei[K_PT], ej[K_PT];
    #pragma unroll
    for (int k = 0; k < K_PT; ++k) {
        const int e = be0 + k * BLK + threadIdx.x;
        ei[k] = -1; ej[k] = -1;
        if (e < be1) {
            ei[k] = idx_i[e];
            ej[k] = idx_j[e];
            atomicAdd(&hist[ei[k] / APB], 1);
            atomicAdd(&hist[ej[k] / APB], 1);
        }
    }
    __syncthreads();                       // histogram complete (r11 lesson)

    // ---- wave-0 exclusive scan over NB=128 (2 entries/lane, shfl)
    if (threadIdx.x < 64) {
        const int l = threadIdx.x;
        const int a = hist[2 * l], b = hist[2 * l + 1];
        int s = a + b;
        #pragma unroll
        for (int off = 1; off < 64; off <<= 1) {
            const int v = __shfl_up(s, off, 64);
            if (l >= off) s += v;
        }
        const int excl_pair = s - (a + b);
        excl[2 * l]     = excl_pair;
        excl[2 * l + 1] = excl_pair + a;
    }
    __syncthreads();

    // ---- reservation: one global atomic per non-empty bucket
    for (int t = threadIdx.x; t < NB; t += blockDim.x) {
        const int h  = hist[t];
        const int ex = excl[t];
        const int g  = h ? atomicAdd(&cnt[t], h) : 0;
        cur[t]    = ex;
        shiftb[t] = t * CAP + g - ex;     // rec idx = stg idx + shift
    }
    __syncthreads();

    // ---- phase 2: float loads, stress accum, 8B bucket-major staging
    #pragma unroll
    for (int k = 0; k < K_PT; ++k) {
        const int e = be0 + k * BLK + threadIdx.x;
        if (e >= be1) continue;
        const int i = ei[k], j = ej[k];
        const float dx = dEdRij[3*e+0], dy = dEdRij[3*e+1], dz = dEdRij[3*e+2];
        const float rx = Rij[3*e+0],    ry = Rij[3*e+1],    rz = Rij[3*e+2];

        const int m = idx_m[i];
        float* s = &smem[m * 9];
        atomicAdd(&s[0], rx * dx);
        atomicAdd(&s[1], rx * dy);
        atomicAdd(&s[2], rx * dz);
        atomicAdd(&s[3], ry * dx);
        atomicAdd(&s[4], ry * dy);
        atomicAdd(&s[5], ry * dz);
        atomicAdd(&s[6], rz * dx);
        atomicAdd(&s[7], rz * dy);
        atomicAdd(&s[8], rz * dz);

        const int bi = i / APB;
        const int li = i - bi * APB;
        uint2 q;
        q.x = ((unsigned)li << 16) | h16(dx);
        q.y = (unsigned)h16(dy) | ((unsigned)h16(dz) << 16);
        int p = atomicAdd(&cur[bi], 1);
        stg[p] = q; stgb[p] = (unsigned char)bi;

        const int bj = j / APB;
        const int lj = j - bj * APB;
        q.x = ((unsigned)lj << 16) | h16(-dx);
        q.y = (unsigned)h16(-dy) | ((unsigned)h16(-dz) << 16);
        p = atomicAdd(&cur[bj], 1);
        stg[p] = q; stgb[p] = (unsigned char)bj;
    }
    __syncthreads();

    // ---- stream-out: bucket-major runs -> coalesced
    const int total = 2 * (be1 - be0);
    for (int t = threadIdx.x; t < total; t += blockDim.x) {
        const int b = stgb[t];
        const int gidx = t + shiftb[b];
        if (gidx < (b + 1) * CAP)          // capacity guard (drop-only)
            rec[gidx] = stg[t];
    }

    __syncthreads();
    float* sp = spart + (size_t)blockIdx.x * STRESS_FLOATS;
    for (int t = threadIdx.x; t < STRESS_FLOATS; t += blockDim.x)
        sp[t] += smem[t];
}

// ---------------------------------------------------------------------------
// Pass D (r16, measured ~60-70us/chunk): S blocks per bucket, uint4 paired
// loads, 8-deep unroll. store=1 on chunk 0 (no pre-zero, no RMW read).
// ---------------------------------------------------------------------------
__global__ void __launch_bounds__(256)
accum_kernel(const uint2* __restrict__ rec,
             const int*   __restrict__ cnt,
             float* __restrict__ partial,   // [S][NPAD*3]
             int CAP, int S, int store)
{
    __shared__ float facc[APB * 3];        // 18.8 KB
    const int b = blockIdx.x / S;
    const int s = blockIdx.x - b * S;
    for (int t = threadIdx.x; t < APB * 3; t += blockDim.x) facc[t] = 0.f;
    __syncthreads();

    int n = cnt[b];
    if (n > CAP) n = CAP;
    int r0 = (int)((long long)n * s / S);
    int r1 = (int)((long long)n * (s + 1) / S);
    const uint2* rb = rec + (size_t)b * CAP;

#define ACC1(w0, w1)                                                  \
    {                                                                 \
        const int   l  = (int)((w0) >> 16);                           \
        const float fx = __half2float(__ushort_as_half(               \
                             (unsigned short)((w0) & 0xffffu)));      \
        const float fy = __half2float(__ushort_as_half(               \
                             (unsigned short)((w1) & 0xffffu)));      \
        const float fz = __half2float(__ushort_as_half(               \
                             (unsigned short)((w1) >> 16)));          \
        atomicAdd(&facc[l * 3 + 0], fx);                              \
        atomicAdd(&facc[l * 3 + 1], fy);                              \
        atomicAdd(&facc[l * 3 + 2], fz);                              \
    }

    if (r0 < r1 && (r0 & 1)) {
        if (threadIdx.x == 0) { const uint2 q = rb[r0]; ACC1(q.x, q.y); }
        ++r0;
    }
    if (r0 < r1 && (r1 & 1)) {
        --r1;
        if (threadIdx.x == 0) { const uint2 q = rb[r1]; ACC1(q.x, q.y); }
    }
    const int npair = (r1 - r0) >> 1;
    const uint4* rp = (const uint4*)(rb + r0);

    int p = threadIdx.x;
    for (; p + 7 * BLK < npair; p += 8 * BLK) {
        uint4 q0 = rp[p];
        uint4 q1 = rp[p + 1 * BLK];
        uint4 q2 = rp[p + 2 * BLK];
        uint4 q3 = rp[p + 3 * BLK];
        uint4 q4 = rp[p + 4 * BLK];
        uint4 q5 = rp[p + 5 * BLK];
        uint4 q6 = rp[p + 6 * BLK];
        uint4 q7 = rp[p + 7 * BLK];
        ACC1(q0.x, q0.y); ACC1(q0.z, q0.w);
        ACC1(q1.x, q1.y); ACC1(q1.z, q1.w);
        ACC1(q2.x, q2.y); ACC1(q2.z, q2.w);
        ACC1(q3.x, q3.y); ACC1(q3.z, q3.w);
        ACC1(q4.x, q4.y); ACC1(q4.z, q4.w);
        ACC1(q5.x, q5.y); ACC1(q5.z, q5.w);
        ACC1(q6.x, q6.y); ACC1(q6.z, q6.w);
        ACC1(q7.x, q7.y); ACC1(q7.z, q7.w);
    }
    for (; p < npair; p += BLK) {
        const uint4 q = rp[p];
        ACC1(q.x, q.y); ACC1(q.z, q.w);
    }
#undef ACC1

    __syncthreads();
    float* pp = partial + ((size_t)s * NPAD + (size_t)b * APB) * 3;
    if (store) {
        for (int t = threadIdx.x; t < APB * 3; t += blockDim.x)
            pp[t] = facc[t];
    } else {
        for (int t = threadIdx.x; t < APB * 3; t += blockDim.x)
            pp[t] += facc[t];
    }
}

// ---------------------------------------------------------------------------
__global__ void final_forces_kernel(const float* __restrict__ partial,
                                    float* __restrict__ forces, int n3, int S)
{
    const int t = blockIdx.x * blockDim.x + threadIdx.x;
    if (t >= n3) return;
    float a = 0.f;
    for (int s = 0; s < S; ++s)
        a += partial[(size_t)s * NPAD * 3 + t];
    forces[t] = a;
}

// ---------------------------------------------------------------------------
// Stress reduce, 2-stage. RS_SLICES=64 -> stage1 serial depth ~76 rows.
// ---------------------------------------------------------------------------
__global__ void reduce_stress_stage1(const float* __restrict__ spart,
                                     float* __restrict__ stmp, int rows)
{
    const int t = blockIdx.x * blockDim.x + threadIdx.x;
    if (t >= STRESS_FLOATS * RS_SLICES) return;
    const int col = t % STRESS_FLOATS;
    const int sl  = t / STRESS_FLOATS;
    float acc = 0.f;
    for (int r = sl; r < rows; r += RS_SLICES)
        acc += spart[(size_t)r * STRESS_FLOATS + col];
    stmp[sl * STRESS_FLOATS + col] = acc;
}

__global__ void reduce_stress_stage2(const float* __restrict__ stmp,
                                     const float* __restrict__ cell,
                                     float* __restrict__ out_stress)
{
    const int t = blockIdx.x * blockDim.x + threadIdx.x;
    if (t >= STRESS_FLOATS) return;
    float acc = 0.f;
    for (int s = 0; s < RS_SLICES; ++s)
        acc += stmp[s * STRESS_FLOATS + t];
    const int m = t / 9;
    const float* c = &cell[m * 9];
    const float a0 = c[0], a1 = c[1], a2 = c[2];
    const float b0 = c[3], b1 = c[4], b2 = c[5];
    const float c0 = c[6], c1 = c[7], c2 = c[8];
    const float x0 = b1 * c2 - b2 * c1;
    const float x1 = b2 * c0 - b0 * c2;
    const float x2 = b0 * c1 - b1 * c0;
    const float vol = a0 * x0 + a1 * x1 + a2 * x2;
    out_stress[t] = acc / vol;
}

// ===========================================================================
// Fallback: round-6 measured f64 atomic path (known passing)
// ===========================================================================
__global__ void zero_f64_kernel(double* __restrict__ p, int n) {
    int i = blockIdx.x * blockDim.x + threadIdx.x;
    if (i < n) p[i] = 0.0;
}

__global__ void __launch_bounds__(256)
edge_kernel_f64(const float* __restrict__ dEdRij,
                const float* __restrict__ Rij,
                const int*   __restrict__ idx_i,
                const int*   __restrict__ idx_j,
                const int*   __restrict__ idx_m,
                double* __restrict__ facc,
                float*  __restrict__ spart,
                int E)
{
    __shared__ float smem[STRESS_FLOATS];
    for (int t = threadIdx.x; t < STRESS_FLOATS; t += blockDim.x) smem[t] = 0.f;
    __syncthreads();
    const int stride = gridDim.x * blockDim.x;
    for (int e = blockIdx.x * blockDim.x + threadIdx.x; e < E; e += stride) {
        const int i = idx_i[e], j = idx_j[e];
        const float dx = dEdRij[3*e+0], dy = dEdRij[3*e+1], dz = dEdRij[3*e+2];
        const float rx = Rij[3*e+0],    ry = Rij[3*e+1],    rz = Rij[3*e+2];
        double* fi = facc + 3 * (size_t)i;
        unsafeAtomicAdd(fi + 0, (double) dx);
        unsafeAtomicAdd(fi + 1, (double) dy);
        unsafeAtomicAdd(fi + 2, (double) dz);
        double* fj = facc + 3 * (size_t)j;
        unsafeAtomicAdd(fj + 0, (double)-dx);
        unsafeAtomicAdd(fj + 1, (double)-dy);
        unsafeAtomicAdd(fj + 2, (double)-dz);
        const int m = idx_m[i];
        float* s = &smem[m * 9];
        atomicAdd(&s[0], rx*dx); atomicAdd(&s[1], rx*dy); atomicAdd(&s[2], rx*dz);
        atomicAdd(&s[3], ry*dx); atomicAdd(&s[4], ry*dy); atomicAdd(&s[5], ry*dz);
        atomicAdd(&s[6], rz*dx); atomicAdd(&s[7], rz*dy); atomicAdd(&s[8], rz*dz);
    }
    __syncthreads();
    float* sp = spart + (size_t)blockIdx.x * STRESS_FLOATS;
    for (int t = threadIdx.x; t < STRESS_FLOATS; t += blockDim.x) sp[t] = smem[t];
}

__global__ void reduce_forces_f64_kernel(const double* __restrict__ facc,
                                         float* __restrict__ forces, int n3)
{
    int t = blockIdx.x * blockDim.x + threadIdx.x;
    if (t < n3) forces[t] = (float)facc[t];
}

// ===========================================================================
extern "C" void kernel_launch(void* const* d_in, const int* in_sizes, int n_in,
                              void* d_out, int out_size, void* d_ws, size_t ws_size,
                              hipStream_t stream)
{
    const float* dEdRij = (const float*)d_in[0];
    const float* Rij    = (const float*)d_in[1];
    const float* R      = (const float*)d_in[2];  (void)R;
    const float* cell   = (const float*)d_in[3];
    const int*   idx_i  = (const int*)d_in[4];
    const int*   idx_j  = (const int*)d_in[5];
    const int*   idx_m  = (const int*)d_in[6];

    const int E  = in_sizes[0] / 3;   // 10,000,000
    const int N  = in_sizes[2] / 3;   // 200,000
    const int n3 = N * 3;

    float* out        = (float*)d_out;
    float* forces     = out;
    float* stress_out = out + (size_t)n3;

    // ---- (nc, S) priority search. need =
    //  rec[NB][CAP]*8B + spart[ROWS][1152]*4B + cnt[nc][NB]*4B
    //  + stmp[64][1152]*4B + partial[S][NPAD*3]*4B
    int nchunks = 0, SEG = 0, CAP = 0, ROWS = 0;
    size_t rec_u2 = 0, spart_f = 0;
    {
        const int cand[14][2] = {
            {2,8},{2,4},{3,8},{3,4},{4,8},{4,4},{2,2},{5,4},
            {8,4},{8,2},{10,2},{16,2},{20,2},{40,1}};
        for (int ci = 0; ci < 14; ++ci) {
            const int nc = cand[ci][0];
            const int S  = cand[ci][1];
            const int CH = (E + nc - 1) / nc;
            const long long mean = 2LL * CH / NB;
            int cap = (int)(mean + mean / 16 + 64);  // ~17+ sigma headroom
            cap = (cap + 1) & ~1;                    // even: 16B pair alignment
            const int rows = (CH + EPB - 1) / EPB;
            const size_t need = (size_t)NB * cap * sizeof(uint2)
                              + (size_t)rows * STRESS_FLOATS * sizeof(float)
                              + (size_t)nc * NB * sizeof(int)
                              + (size_t)RS_SLICES * STRESS_FLOATS * sizeof(float)
                              + (size_t)S * NPAD * 3 * sizeof(float)
                              + 256;
            if (need <= ws_size) {
                nchunks = nc; SEG = S; CAP = cap; ROWS = rows;
                rec_u2  = (size_t)NB * cap;
                spart_f = (size_t)rows * STRESS_FLOATS;
                break;
            }
        }
    }

    if (nchunks > 0) {
        uint2* rec   = (uint2*)d_ws;
        float* spart = (float*)(rec + rec_u2);
        int*   cnt   = (int*)(spart + spart_f);               // [nc][NB]
        float* stmp  = (float*)(cnt + (size_t)nchunks * NB);  // [64][1152]
        float* part  = stmp + (size_t)RS_SLICES * STRESS_FLOATS; // [S][NPAD*3]

        // zero spart + cnt (contiguous); stmp/partial fully overwritten
        const size_t zf = spart_f + (size_t)nchunks * NB;
        zero_f32_kernel<<<(int)((zf + BLK - 1) / BLK), BLK, 0, stream>>>(
            spart, zf);

        const int CH = (E + nchunks - 1) / nchunks;
        int chunk = 0;
        for (int s = 0; s < E; s += CH, ++chunk) {
            const int ce = min(CH, E - s);
            const int nb = (ce + EPB - 1) / EPB;

            scatter_kernel<<<nb, BLK, 0, stream>>>(
                dEdRij, Rij, idx_i, idx_j, idx_m,
                rec, cnt + (size_t)chunk * NB, spart, s, ce, CAP);

            accum_kernel<<<NB * SEG, BLK, 0, stream>>>(
                rec, cnt + (size_t)chunk * NB, part, CAP, SEG,
                chunk == 0 ? 1 : 0);
        }

        final_forces_kernel<<<(n3 + BLK - 1) / BLK, BLK, 0, stream>>>(
            part, forces, n3, SEG);
        reduce_stress_stage1<<<(STRESS_FLOATS * RS_SLICES + BLK - 1) / BLK,
                               BLK, 0, stream>>>(spart, stmp, ROWS);
        reduce_stress_stage2<<<(STRESS_FLOATS + BLK - 1) / BLK, BLK, 0, stream>>>(
            stmp, cell, stress_out);
    } else {
        // fallback: measured f64 atomic path
        double* facc   = (double*)d_ws;
        float*  spartf = (float*)(facc + n3);

        zero_f64_kernel<<<(n3 + BLK - 1) / BLK, BLK, 0, stream>>>(facc, n3);
        edge_kernel_f64<<<2048, BLK, 0, stream>>>(
            dEdRij, Rij, idx_i, idx_j, idx_m, facc, spartf, E);
        reduce_forces_f64_kernel<<<(n3 + BLK - 1) / BLK, BLK, 0, stream>>>(
            facc, forces, n3);
        reduce_stress_stage1<<<(STRESS_FLOATS * RS_SLICES + BLK - 1) / BLK,
                               BLK, 0, stream>>>(
            spartf, (float*)(spartf + (size_t)2048 * STRESS_FLOATS), 2048);
        reduce_stress_stage2<<<(STRESS_FLOATS + BLK - 1) / BLK, BLK, 0, stream>>>(
            (float*)(spartf + (size_t)2048 * STRESS_FLOATS), cell, stress_out);
    }
}